// Round 4
// baseline (348.580 us; speedup 1.0000x reference)
//
#include <hip/hip_runtime.h>

// out[b,l] = bias[l] + sum_i x_i W1[i,l] + sum_ij x_i x_j W2[i,j,l]
//          + sum_ijk x_i x_j x_k W3[i,j,k,l];  B=32768, D=K=32, fp32 in/out.
//
// Feature-GEMM over unordered pairs (i<=j) of xt=[x,1] (33 symbols, 561 pairs),
// v_mfma_f32_32x32x16_f16, fp32 accumulate. R4: all f16 math through native
// _Float16 ext-vectors (R3's __half2 ops promoted to f32: ~139 VALU instr/pair
// measured vs ~20 written -> VALU-issue-bound at 54% busy). 16-wave blocks for
// 4 waves/SIMD occupancy; 8-way pair split {g,15-g,16+g,31-g,32}.

typedef _Float16 f16;
typedef __attribute__((ext_vector_type(2)))  _Float16 f16x2;
typedef __attribute__((ext_vector_type(4)))  _Float16 f16x4;
typedef __attribute__((ext_vector_type(8)))  _Float16 f16x8;
typedef __attribute__((ext_vector_type(16))) float    f32x16;

union AV { f16x2 h2[4];  f16x8 v;    };
union XR { f16x2 h2[16]; f16x8 v[4]; };

// group g (0..7) runs: pi = {g, 15-g, 16+g, 31-g, [32 iff g==0]}
// pair counts: g0=71, g1..g7=70.  GBASE(g) = g ? 1+70g : 0.
__device__ __forceinline__ int run_pi(int g, int rr) {
    return rr == 0 ? g : rr == 1 ? 15 - g : rr == 2 ? 16 + g : rr == 3 ? 31 - g : 32;
}

// ---------------- prep: per-group sequential coefficient streams ----------------
// Slot layout (2048 B): [khalf(2)][col(32)][k16(16)] f16; slot order = group
// stream order (runs in rr order, j ascending).
__global__ void ntl_prep(const float* __restrict__ W1, const float* __restrict__ W2,
                         const float* __restrict__ W3, f16* __restrict__ Gimg) {
    int tid = blockIdx.x * 256 + threadIdx.x;
    if (tid >= 561 * 1024) return;
    int k    = tid & 31;
    int col  = (tid >> 5) & 31;
    int slot = tid >> 10;
    int g = 0;
    while (g < 7 && slot >= 1 + 70 * (g + 1)) ++g;
    int s = slot - (g ? 1 + 70 * g : 0);
    int rr = 0, pi, len;
    for (;;) { pi = run_pi(g, rr); len = 33 - pi; if (s < len) break; s -= len; ++rr; }
    int j = pi + s;             // pi <= j <= 32
    float v;
    if (j < 32) {
        v = W3[((pi * 32 + j) * 32 + k) * 32 + col];
        if (pi != j) v += W3[((j * 32 + pi) * 32 + k) * 32 + col];
    } else if (pi < 32) {
        v = W2[(pi * 32 + k) * 32 + col];
    } else {
        v = W1[k * 32 + col];
    }
    Gimg[slot * 1024 + (k >> 4) * 512 + col * 16 + (k & 15)] = (f16)v;
}

// ---------------- main kernel ----------------
// grid 256 x 1024 (16 waves). Block = 128 rows. Wave w: g=w>>1 (8 pair groups),
// gw=w&1 -> rows gw*64..+63 (2 MFMA row tiles). Main loop: zero LDS, zero
// barriers; B operand streamed from the L2-resident image, x in registers.

#define XE(XR_, J) (((J) & 1) ? (XR_).h2[(J) >> 1][1] : (XR_).h2[(J) >> 1][0])
#define MM(ACC, A, B) (ACC) = __builtin_amdgcn_mfma_f32_32x32x16_f16((A), (B), (ACC), 0, 0, 0)

#define PB(J)                                                                          \
    {                                                                                  \
        if ((J) < 32) { /* prefetch next pair into opposite-parity regs */             \
            if (((J) & 1) == 0) { boa = *(const f16x8*)gp; bob = *(const f16x8*)(gp + 1024); } \
            else                { bea = *(const f16x8*)gp; beb = *(const f16x8*)(gp + 1024); } \
            gp += 2048;                                                                \
        }                                                                              \
        const f16x8 Ba = ((J) & 1) ? boa : bea;                                        \
        const f16x8 Bb = ((J) & 1) ? bob : beb;                                        \
        if ((J) == 32) { /* xt_j = 1: A-frag = yk directly */                          \
            MM(acc0, yk0[0].v, Ba); MM(acc0, yk0[1].v, Bb);                            \
            MM(acc1, yk1[0].v, Ba); MM(acc1, yk1[1].v, Bb);                            \
        } else {                                                                       \
            f16 t0 = XE(xa, (J)); f16x2 xj0 = {t0, t0};                                \
            f16 t1 = XE(xb, (J)); f16x2 xj1 = {t1, t1};                                \
            AV a;                                                                      \
            a.h2[0] = xj0 * yk0[0].h2[0]; a.h2[1] = xj0 * yk0[0].h2[1];                \
            a.h2[2] = xj0 * yk0[0].h2[2]; a.h2[3] = xj0 * yk0[0].h2[3];                \
            MM(acc0, a.v, Ba);                                                         \
            a.h2[0] = xj0 * yk0[1].h2[0]; a.h2[1] = xj0 * yk0[1].h2[1];                \
            a.h2[2] = xj0 * yk0[1].h2[2]; a.h2[3] = xj0 * yk0[1].h2[3];                \
            MM(acc0, a.v, Bb);                                                         \
            a.h2[0] = xj1 * yk1[0].h2[0]; a.h2[1] = xj1 * yk1[0].h2[1];                \
            a.h2[2] = xj1 * yk1[0].h2[2]; a.h2[3] = xj1 * yk1[0].h2[3];                \
            MM(acc1, a.v, Ba);                                                         \
            a.h2[0] = xj1 * yk1[1].h2[0]; a.h2[1] = xj1 * yk1[1].h2[1];                \
            a.h2[2] = xj1 * yk1[1].h2[2]; a.h2[3] = xj1 * yk1[1].h2[3];                \
            MM(acc1, a.v, Bb);                                                         \
        }                                                                              \
    }

__global__ __launch_bounds__(1024, 4) void ntl_main(const float* __restrict__ X,
                                                    const float* __restrict__ bias,
                                                    const f16* __restrict__ Gimg,
                                                    float* __restrict__ out) {
    __shared__ f16   xbuf[128 * 40];   // row stride 40 halves (80 B)
    __shared__ float red[7 * 2 * 2 * 16 * 64];   // 114688 B cross-group reduce

    const int tid = (int)threadIdx.x;
    const int w   = tid >> 6;
    const int l   = tid & 63;
    const int g   = w >> 1;      // pair group 0..7
    const int gw  = w & 1;       // row-half
    const int h   = l >> 5;      // k-half
    const int lr  = l & 31;      // A row within tile / B col
    const long rowbase = (long)blockIdx.x * 128;

    // ---- prologue: x tile -> LDS (f16) ----
    {
        int r0 = tid >> 3, cb = (tid & 7) * 4;
        const float* xp = X + (rowbase + r0) * 32 + cb;
        float4 f0 = *(const float4*)xp;
        f16x4 o = {(f16)f0.x, (f16)f0.y, (f16)f0.z, (f16)f0.w};
        *(f16x4*)&xbuf[r0 * 40 + cb] = o;
        if ((tid & 7) == 0) xbuf[r0 * 40 + 32] = (f16)1.0f;
    }
    __syncthreads();

    XR xa, xb;   // this lane's two x rows (halves 0..31), in registers
    {
        const f16x8* p0 = (const f16x8*)&xbuf[(gw * 64 + lr) * 40];
        const f16x8* p1 = (const f16x8*)&xbuf[(gw * 64 + 32 + lr) * 40];
        xa.v[0] = p0[0]; xa.v[1] = p0[1]; xa.v[2] = p0[2]; xa.v[3] = p0[3];
        xb.v[0] = p1[0]; xb.v[1] = p1[1]; xb.v[2] = p1[2]; xb.v[3] = p1[3];
    }

    f32x16 acc0, acc1;
#pragma unroll
    for (int q = 0; q < 16; ++q) { acc0[q] = 0.f; acc1[q] = 0.f; }

    const char* gp = (const char*)Gimg + (size_t)(g ? 1 + 70 * g : 0) * 2048 + lr * 32 + h * 16;
    f16x8 bea{}, beb{}, boa{}, bob{};
    const int nr = (g == 0) ? 5 : 4;

    for (int rr = 0; rr < nr; ++rr) {
        const int pi = run_pi(g, rr);
        f16 xp0 = xbuf[(gw * 64 + lr) * 40 + pi];
        f16 xp1 = xbuf[(gw * 64 + 32 + lr) * 40 + pi];
        f16x2 hp0 = {xp0, xp0}, hp1 = {xp1, xp1};
        AV yk0[2], yk1[2];   // run-invariant x_pi * x[k-slice], MFMA A layout
#pragma unroll
        for (int kh = 0; kh < 2; ++kh)
#pragma unroll
            for (int q = 0; q < 4; ++q) {
                yk0[kh].h2[q] = hp0 * (h ? xa.h2[kh * 8 + 4 + q] : xa.h2[kh * 8 + q]);
                yk1[kh].h2[q] = hp1 * (h ? xb.h2[kh * 8 + 4 + q] : xb.h2[kh * 8 + q]);
            }
        // head loads for pair (pi,pi) into parity buffer pi&1
        if (pi & 1) { boa = *(const f16x8*)gp; bob = *(const f16x8*)(gp + 1024); }
        else        { bea = *(const f16x8*)gp; beb = *(const f16x8*)(gp + 1024); }
        gp += 2048;

        switch (pi) {
            case 0:  PB(0)
            case 1:  PB(1)
            case 2:  PB(2)
            case 3:  PB(3)
            case 4:  PB(4)
            case 5:  PB(5)
            case 6:  PB(6)
            case 7:  PB(7)
            case 8:  PB(8)
            case 9:  PB(9)
            case 10: PB(10)
            case 11: PB(11)
            case 12: PB(12)
            case 13: PB(13)
            case 14: PB(14)
            case 15: PB(15)
            case 16: PB(16)
            case 17: PB(17)
            case 18: PB(18)
            case 19: PB(19)
            case 20: PB(20)
            case 21: PB(21)
            case 22: PB(22)
            case 23: PB(23)
            case 24: PB(24)
            case 25: PB(25)
            case 26: PB(26)
            case 27: PB(27)
            case 28: PB(28)
            case 29: PB(29)
            case 30: PB(30)
            case 31: PB(31)
            case 32: PB(32)
        }
    }

    // ---- cross-group reduce: groups 1..7 dump, group 0 adds + bias + stores ----
    if (g >= 1) {
        int base = ((g - 1) * 4 + gw * 2) * 16 * 64;
#pragma unroll
        for (int r = 0; r < 16; ++r) red[base + r * 64 + l] = acc0[r];
#pragma unroll
        for (int r = 0; r < 16; ++r) red[base + (16 + r) * 64 + l] = acc1[r];
    }
    __syncthreads();
    if (g == 0) {
        float bcol = bias[lr];
#pragma unroll
        for (int r = 0; r < 16; ++r) {
            int rowoff = (r & 3) + 8 * (r >> 2) + 4 * h;   // D layout (verified R2/R3)
            {
                float v = acc0[r] + bcol;
#pragma unroll
                for (int sg = 0; sg < 7; ++sg)
                    v += red[((sg * 4 + gw * 2) * 16 + r) * 64 + l];
                out[(rowbase + gw * 64 + rowoff) * 32 + lr] = v;
            }
            {
                float v = acc1[r] + bcol;
#pragma unroll
                for (int sg = 0; sg < 7; ++sg)
                    v += red[((sg * 4 + gw * 2 + 1) * 16 + r) * 64 + l];
                out[(rowbase + gw * 64 + 32 + rowoff) * 32 + lr] = v;
            }
        }
    }
}

extern "C" void kernel_launch(void* const* d_in, const int* in_sizes, int n_in,
                              void* d_out, int out_size, void* d_ws, size_t ws_size,
                              hipStream_t stream) {
    const float* X    = (const float*)d_in[0];
    const float* W1   = (const float*)d_in[1];
    const float* W2   = (const float*)d_in[2];
    const float* W3   = (const float*)d_in[3];
    const float* bias = (const float*)d_in[4];
    float* out = (float*)d_out;
    f16* Gimg = (f16*)d_ws;   // 561 * 2048 B = 1.15 MB

    int prep_threads = 561 * 1024;
    ntl_prep<<<dim3((prep_threads + 255) / 256), dim3(256), 0, stream>>>(W1, W2, W3, Gimg);
    ntl_main<<<dim3(256), dim3(1024), 0, stream>>>(X, bias, Gimg, out);
}

// Round 5
// 71.465 us; speedup vs baseline: 4.8777x; 4.8777x over previous
//
#include <hip/hip_runtime.h>

// out[b,l] = bias[l] + sum_i x_i W1[i,l] + sum_ij x_i x_j W2[i,j,l]
//          + sum_ijk x_i x_j x_k W3[i,j,k,l];  B=32768, D=K=32, fp32 in/out.
//
// Feature-GEMM over unordered pairs (i<=j) of xt=[x,1] (33 symbols, 561 pairs),
// v_mfma_f32_32x32x16_f16, fp32 accumulate.
// R5 = R3 geometry (grid 256 x 512thr, lb(512,2): VGPR 128, no spill; R4's
// lb(1024,4) forced 64 VGPR -> 840 MB scratch traffic, 6x regression)
//    + native _Float16 math (R3's __half2 promoted through f32: ~139 VALU
//      instr/pair measured vs ~20 written -> 33 us of VALU issue)
//    + depth-2 B prefetch (4 rotating literal-indexed reg buffers; lead
//      ~250 cyc > ~200 cyc L2 latency; occupancy is grid-capped at 2
//      waves/SIMD so the +16 VGPR are free).

typedef _Float16 f16;
typedef __attribute__((ext_vector_type(4)))  _Float16 f16x4;
typedef __attribute__((ext_vector_type(8)))  _Float16 f16x8;
typedef __attribute__((ext_vector_type(2)))  _Float16 f16x2;
typedef __attribute__((ext_vector_type(16))) float    f32x16;

union AV { f16x2 h2[4];  f16x8 v;    };
union XR { f16x2 h2[16]; f16x8 v[4]; };

// 4 pair-groups; group g runs pi = {g, 7-g, 8+g, 15-g, 16+g, 23-g, 24+g, 31-g,
// [32 iff g==0]}; pair counts 141/140/140/140. Stream base = g ? 140g+1 : 0.
__device__ __forceinline__ int run_pi(int g, int rr) {
    switch (rr) {
        case 0: return g;      case 1: return 7 - g;  case 2: return 8 + g;
        case 3: return 15 - g; case 4: return 16 + g; case 5: return 23 - g;
        case 6: return 24 + g; case 7: return 31 - g; default: return 32;
    }
}

// ---------------- prep: per-group sequential coefficient streams ----------------
// Slot (2048 B): [khalf(2)][col(32)][k16(16)] f16; slot order = group stream
// order (runs in rr order, j ascending).
__global__ void ntl_prep(const float* __restrict__ W1, const float* __restrict__ W2,
                         const float* __restrict__ W3, f16* __restrict__ Gimg) {
    int tid = blockIdx.x * 256 + threadIdx.x;
    if (tid >= 561 * 1024) return;
    int k    = tid & 31;
    int col  = (tid >> 5) & 31;
    int slot = tid >> 10;
    int g = 0;
    while (g < 3 && slot >= 141 + 140 * g) ++g;
    int s = slot - (g ? 140 * g + 1 : 0);
    int rr = 0, pi, len;
    for (;;) { pi = run_pi(g, rr); len = 33 - pi; if (s < len) break; s -= len; ++rr; }
    int j = pi + s;             // pi <= j <= 32
    float v;
    if (j < 32) {
        v = W3[((pi * 32 + j) * 32 + k) * 32 + col];
        if (pi != j) v += W3[((j * 32 + pi) * 32 + k) * 32 + col];
    } else if (pi < 32) {
        v = W2[(pi * 32 + k) * 32 + col];
    } else {
        v = W1[k * 32 + col];
    }
    Gimg[slot * 1024 + (k >> 4) * 512 + col * 16 + (k & 15)] = (f16)v;
}

// ---------------- main kernel ----------------
// grid 256 x 512 (8 waves). Block = 128 rows. Wave w: g=w>>1 (4 pair groups),
// gw=w&1 -> rows gw*64..+63 (2 MFMA row tiles). Main loop: no LDS traffic, no
// barriers; B streamed from the L2-resident image, x rows in registers.

#define XE(XR_, J) ((XR_).h2[(J) >> 1][(J) & 1])
#define MM(ACC, A, B) (ACC) = __builtin_amdgcn_mfma_f32_32x32x16_f16((A), (B), (ACC), 0, 0, 0)

// load next slot into rotating buffer IDX
#define LD(IDX) { b##IDX##a = *(const f16x8*)gp; b##IDX##b = *(const f16x8*)(gp + 1024); gp += 2048; }

// pair body: consume buffer C (=J&3), prefetch J+2 into P (=(J+2)&3)
#define PB(J, C, P)                                                                    \
    {                                                                                  \
        if ((J) + 2 <= 32) { LD(P) }                                                   \
        const f16x8 Ba = b##C##a;                                                      \
        const f16x8 Bb = b##C##b;                                                      \
        if ((J) == 32) { /* xt_j = 1: A-frag = yk directly */                          \
            MM(acc0, yk0[0].v, Ba); MM(acc0, yk0[1].v, Bb);                            \
            MM(acc1, yk1[0].v, Ba); MM(acc1, yk1[1].v, Bb);                            \
        } else {                                                                       \
            f16 t0 = XE(xa, (J)); f16x2 xj0 = {t0, t0};                                \
            f16 t1 = XE(xb, (J)); f16x2 xj1 = {t1, t1};                                \
            AV a;                                                                      \
            a.h2[0] = xj0 * yk0[0].h2[0]; a.h2[1] = xj0 * yk0[0].h2[1];                \
            a.h2[2] = xj0 * yk0[0].h2[2]; a.h2[3] = xj0 * yk0[0].h2[3];                \
            MM(acc0, a.v, Ba);                                                         \
            a.h2[0] = xj0 * yk0[1].h2[0]; a.h2[1] = xj0 * yk0[1].h2[1];                \
            a.h2[2] = xj0 * yk0[1].h2[2]; a.h2[3] = xj0 * yk0[1].h2[3];                \
            MM(acc0, a.v, Bb);                                                         \
            a.h2[0] = xj1 * yk1[0].h2[0]; a.h2[1] = xj1 * yk1[0].h2[1];                \
            a.h2[2] = xj1 * yk1[0].h2[2]; a.h2[3] = xj1 * yk1[0].h2[3];                \
            MM(acc1, a.v, Ba);                                                         \
            a.h2[0] = xj1 * yk1[1].h2[0]; a.h2[1] = xj1 * yk1[1].h2[1];                \
            a.h2[2] = xj1 * yk1[1].h2[2]; a.h2[3] = xj1 * yk1[1].h2[3];                \
            MM(acc1, a.v, Bb);                                                         \
        }                                                                              \
    }

__global__ __launch_bounds__(512, 2) void ntl_main(const float* __restrict__ X,
                                                   const float* __restrict__ bias,
                                                   const f16* __restrict__ Gimg,
                                                   float* __restrict__ out) {
    __shared__ f16   xbuf[128 * 40];   // row stride 40 halves (80 B)
    __shared__ float red[12288];       // 48 KB cross-group reduction buffer

    const int tid = (int)threadIdx.x;
    const int w   = tid >> 6;
    const int l   = tid & 63;
    const int g   = w >> 1;      // pair group 0..3
    const int gw  = w & 1;       // row-half
    const int h   = l >> 5;      // k-half
    const int lr  = l & 31;      // A row within tile / B col
    const long rowbase = (long)blockIdx.x * 128;

    // ---- prologue: x tile -> LDS (f16) ----
    {
        int r0 = tid >> 2, cb = (tid & 3) * 8;
        const float* xp = X + (rowbase + r0) * 32 + cb;
        float4 f0 = *(const float4*)xp;
        float4 f1 = *(const float4*)(xp + 4);
        f16x4 o0 = {(f16)f0.x, (f16)f0.y, (f16)f0.z, (f16)f0.w};
        f16x4 o1 = {(f16)f1.x, (f16)f1.y, (f16)f1.z, (f16)f1.w};
        *(f16x4*)&xbuf[r0 * 40 + cb]     = o0;
        *(f16x4*)&xbuf[r0 * 40 + cb + 4] = o1;
        if ((tid & 3) == 0) xbuf[r0 * 40 + 32] = (f16)1.0f;
    }
    __syncthreads();

    XR xa, xb;   // this lane's two x rows (halves 0..31), in registers
    {
        const f16x8* p0 = (const f16x8*)&xbuf[(gw * 64 + lr) * 40];
        const f16x8* p1 = (const f16x8*)&xbuf[(gw * 64 + 32 + lr) * 40];
        xa.v[0] = p0[0]; xa.v[1] = p0[1]; xa.v[2] = p0[2]; xa.v[3] = p0[3];
        xb.v[0] = p1[0]; xb.v[1] = p1[1]; xb.v[2] = p1[2]; xb.v[3] = p1[3];
    }

    f32x16 acc0, acc1;
#pragma unroll
    for (int q = 0; q < 16; ++q) { acc0[q] = 0.f; acc1[q] = 0.f; }

    const char* gp = (const char*)Gimg + (size_t)(g ? 140 * g + 1 : 0) * 2048 + lr * 32 + h * 16;
    f16x8 b0a{}, b0b{}, b1a{}, b1b{}, b2a{}, b2b{}, b3a{}, b3b{};
    const int nr = (g == 0) ? 9 : 8;

    for (int rr = 0; rr < nr; ++rr) {
        const int pi = run_pi(g, rr);
        f16 xp0 = xbuf[(gw * 64 + lr) * 40 + pi];
        f16 xp1 = xbuf[(gw * 64 + 32 + lr) * 40 + pi];
        f16x2 hp0 = {xp0, xp0}, hp1 = {xp1, xp1};
        AV yk0[2], yk1[2];   // run-invariant x_pi * x[k-slice], MFMA A layout
#pragma unroll
        for (int kh = 0; kh < 2; ++kh)
#pragma unroll
            for (int q = 0; q < 4; ++q) {
                yk0[kh].h2[q] = hp0 * (h ? xa.h2[kh * 8 + 4 + q] : xa.h2[kh * 8 + q]);
                yk1[kh].h2[q] = hp1 * (h ? xb.h2[kh * 8 + 4 + q] : xb.h2[kh * 8 + q]);
            }
        // head: load pairs pi and pi+1 into rotation slots pi&3, (pi+1)&3
        switch (pi & 3) {
            case 0: LD(0) if (pi < 32) LD(1) break;
            case 1: LD(1) LD(2) break;
            case 2: LD(2) LD(3) break;
            case 3: LD(3) LD(0) break;
        }

        switch (pi) {
            case 0:  PB(0, 0, 2)
            case 1:  PB(1, 1, 3)
            case 2:  PB(2, 2, 0)
            case 3:  PB(3, 3, 1)
            case 4:  PB(4, 0, 2)
            case 5:  PB(5, 1, 3)
            case 6:  PB(6, 2, 0)
            case 7:  PB(7, 3, 1)
            case 8:  PB(8, 0, 2)
            case 9:  PB(9, 1, 3)
            case 10: PB(10, 2, 0)
            case 11: PB(11, 3, 1)
            case 12: PB(12, 0, 2)
            case 13: PB(13, 1, 3)
            case 14: PB(14, 2, 0)
            case 15: PB(15, 3, 1)
            case 16: PB(16, 0, 2)
            case 17: PB(17, 1, 3)
            case 18: PB(18, 2, 0)
            case 19: PB(19, 3, 1)
            case 20: PB(20, 0, 2)
            case 21: PB(21, 1, 3)
            case 22: PB(22, 2, 0)
            case 23: PB(23, 3, 1)
            case 24: PB(24, 0, 2)
            case 25: PB(25, 1, 3)
            case 26: PB(26, 2, 0)
            case 27: PB(27, 3, 1)
            case 28: PB(28, 0, 2)
            case 29: PB(29, 1, 3)
            case 30: PB(30, 2, 0)
            case 31: PB(31, 3, 1)
            case 32: PB(32, 0, 2)
        }
    }

    // ---- cross-group reduce: groups 1..3 dump, group 0 adds + bias + stores ----
    if (g >= 1) {
        int base = ((g - 1) * 2 + gw) * 2 * 16 * 64;
#pragma unroll
        for (int r = 0; r < 16; ++r) red[base + r * 64 + l] = acc0[r];
#pragma unroll
        for (int r = 0; r < 16; ++r) red[base + (16 + r) * 64 + l] = acc1[r];
    }
    __syncthreads();
    if (g == 0) {
        float bcol = bias[lr];
#pragma unroll
        for (int r = 0; r < 16; ++r) {
            int rowoff = (r & 3) + 8 * (r >> 2) + 4 * h;   // D layout (verified R2-R4)
            {
                float v = acc0[r] + bcol;
#pragma unroll
                for (int sg = 0; sg < 3; ++sg)
                    v += red[(((sg * 2 + gw) * 2 + 0) * 16 + r) * 64 + l];
                out[(rowbase + gw * 64 + rowoff) * 32 + lr] = v;
            }
            {
                float v = acc1[r] + bcol;
#pragma unroll
                for (int sg = 0; sg < 3; ++sg)
                    v += red[(((sg * 2 + gw) * 2 + 1) * 16 + r) * 64 + l];
                out[(rowbase + gw * 64 + 32 + rowoff) * 32 + lr] = v;
            }
        }
    }
}

extern "C" void kernel_launch(void* const* d_in, const int* in_sizes, int n_in,
                              void* d_out, int out_size, void* d_ws, size_t ws_size,
                              hipStream_t stream) {
    const float* X    = (const float*)d_in[0];
    const float* W1   = (const float*)d_in[1];
    const float* W2   = (const float*)d_in[2];
    const float* W3   = (const float*)d_in[3];
    const float* bias = (const float*)d_in[4];
    float* out = (float*)d_out;
    f16* Gimg = (f16*)d_ws;   // 561 * 2048 B = 1.15 MB

    int prep_threads = 561 * 1024;
    ntl_prep<<<dim3((prep_threads + 255) / 256), dim3(256), 0, stream>>>(W1, W2, W3, Gimg);
    ntl_main<<<dim3(256), dim3(512), 0, stream>>>(X, bias, Gimg, out);
}